// Round 10
// baseline (779.685 us; speedup 1.0000x reference)
//
#include <hip/hip_runtime.h>
#include <stdint.h>

// LSTM B=256,T=2048,D=U=64 fp32. 256 WGs (1 batch) x 256 thr (4 waves).
// R9 (605us) was serial-latency-bound: z lands in lane-group s>>2 each step,
// forcing ds_bpermute c-migration + conditional A rows. R10: A rows are ALL
// the same h vector -> every row of D = h@Wh -> every lane holds z for its
// column at reg 0 EVERY step. State (c,h) replicated across lane groups; no
// bpermute, no migration. xz = bias + X@Wx per 16-step chunk via MFMA
// (rows=timesteps), scattered once to wave-private LDS sXZ[w][s][j][q],
// re-read per step as one broadcast b128 into the MFMA C-init.
// k-map f(g,e)=g*8+e identical on A and B (R9-verified). One lgkm-only
// barrier per step (h cross-wave exchange); vmcnt never drained.

#define T_STEPS 2048
#define DIM     64
#define GATES   256
#define CHUNK   16
#define NCHUNK  (T_STEPS / CHUNK)

typedef _Float16 f16;
typedef _Float16 f16x8 __attribute__((ext_vector_type(8)));
typedef float    f32x4 __attribute__((ext_vector_type(4)));

__device__ __forceinline__ void sync_lds() {
    __builtin_amdgcn_sched_barrier(0);
    asm volatile("s_waitcnt lgkmcnt(0)" ::: "memory");
    __builtin_amdgcn_sched_barrier(0);
    __builtin_amdgcn_s_barrier();
    __builtin_amdgcn_sched_barrier(0);
}

__device__ __forceinline__ float sigm(float z) {
    return __builtin_amdgcn_rcpf(1.f + __expf(-z));
}

#define MFMA16(A, B, C) __builtin_amdgcn_mfma_f32_16x16x32_f16(A, B, C, 0, 0, 0)

__global__ __launch_bounds__(256, 1)
void lstm_rrep_kernel(const float* __restrict__ x,
                      const float* __restrict__ Wx,
                      const float* __restrict__ Wh,
                      const float* __restrict__ bias,
                      float* __restrict__ out)
{
    __shared__ __align__(16) f16   sH[2][64];             // h dbuf (f16)
    __shared__ __align__(16) float sXZ[4][CHUNK][16][4];  // wave-private xz

    const int tid  = threadIdx.x;
    const int lane = tid & 63;
    const int w    = tid >> 6;       // wave 0..3 -> units w*16..+16
    const int j    = lane & 15;      // col-in-tile (B,D) / row (A, xz MFMA)
    const int g    = lane >> 4;      // k-group: k = ks*32 + g*8 + e
    const int u    = w * 16 + j;     // unit

    const int batch = blockIdx.x;
    const float* xb = x + (size_t)batch * T_STEPS * DIM;
    float* ob = out + (size_t)batch * T_STEPS * (2 * DIM);

    // ---- persistent B fragments: col = q*64 + u, k = ks*32 + g*8 + e ----
    f16x8 Bh[4][2], Bx[4][2];
    float bq[4];
#pragma unroll
    for (int q = 0; q < 4; ++q) {
        const int col = q * 64 + u;
        bq[q] = bias[col];
#pragma unroll
        for (int ks = 0; ks < 2; ++ks)
#pragma unroll
            for (int e = 0; e < 8; ++e) {
                const int k = ks * 32 + g * 8 + e;
                Bh[q][ks][e] = (f16)Wh[k * GATES + col];
                Bx[q][ks][e] = (f16)Wx[k * GATES + col];
            }
    }

    if (tid < 128) sH[tid >> 6][tid & 63] = (f16)0.f;

    // ---- chunk 0 A(x) fragments: A[row=ts=j][k], feats g*8.. ----
    f16x8 ax0, ax1;
    {
        const float* xr = xb + (size_t)j * DIM + g * 8;
        float4 x0 = *(const float4*)(xr);
        float4 x1 = *(const float4*)(xr + 4);
        float4 x2 = *(const float4*)(xr + 32);
        float4 x3 = *(const float4*)(xr + 36);
        ax0[0]=(f16)x0.x; ax0[1]=(f16)x0.y; ax0[2]=(f16)x0.z; ax0[3]=(f16)x0.w;
        ax0[4]=(f16)x1.x; ax0[5]=(f16)x1.y; ax0[6]=(f16)x1.z; ax0[7]=(f16)x1.w;
        ax1[0]=(f16)x2.x; ax1[1]=(f16)x2.y; ax1[2]=(f16)x2.z; ax1[3]=(f16)x2.w;
        ax1[4]=(f16)x3.x; ax1[5]=(f16)x3.y; ax1[6]=(f16)x3.z; ax1[7]=(f16)x3.w;
    }

    float c = 0.f;   // replicated: every lane-group's lane j holds c[u]
    __syncthreads();

#define STEP(s) do {                                                         \
        const int pb = (s) & 1;                                              \
        f16x8 A0 = *(const f16x8*)&sH[pb][g * 8];        /* h bcast */       \
        f16x8 A1 = *(const f16x8*)&sH[pb][32 + g * 8];                       \
        float4 xzv = *(const float4*)&sXZ[w][(s)][j][0]; /* bcast b128 */    \
        f32x4 a0 = {xzv.x, xzv.x, xzv.x, xzv.x};                             \
        f32x4 a1 = {xzv.y, xzv.y, xzv.y, xzv.y};                             \
        f32x4 a2 = {xzv.z, xzv.z, xzv.z, xzv.z};                             \
        f32x4 a3 = {xzv.w, xzv.w, xzv.w, xzv.w};                             \
        a0 = MFMA16(A0, Bh[0][0], a0); a0 = MFMA16(A1, Bh[0][1], a0);        \
        a1 = MFMA16(A0, Bh[1][0], a1); a1 = MFMA16(A1, Bh[1][1], a1);        \
        a2 = MFMA16(A0, Bh[2][0], a2); a2 = MFMA16(A1, Bh[2][1], a2);        \
        a3 = MFMA16(A0, Bh[3][0], a3); a3 = MFMA16(A1, Bh[3][1], a3);        \
        float gi = sigm(a0[0]), gf = sigm(a1[0]), go = sigm(a3[0]);          \
        float gg = fmaf(2.f, sigm(a2[0] + a2[0]), -1.f);                     \
        c = fmaf(gf, c, gi * gg);                                            \
        float e2 = __expf(-2.f * fabsf(c));                                  \
        float th = copysignf(                                                \
            fmaf(-2.f, e2 * __builtin_amdgcn_rcpf(1.f + e2), 1.f), c);       \
        float hh = go * th;                                                  \
        const size_t t = (size_t)n * 16 + (s);                               \
        if (g == 2)      sH[pb ^ 1][u] = (f16)hh;        /* next-step h */   \
        else if (g == 0) ob[t * 128 + u]      = c;       /* cell out   */    \
        else if (g == 1) ob[t * 128 + 64 + u] = hh;      /* hidden out */    \
        sync_lds();                                                          \
    } while (0)

#pragma unroll 1
    for (int n = 0; n < NCHUNK; ++n) {
        // ---- xz chunk: acc[q] = bias + X_chunk @ Wx (rows = 16 ts) ----
        f32x4 z0 = {bq[0], bq[0], bq[0], bq[0]};
        f32x4 z1 = {bq[1], bq[1], bq[1], bq[1]};
        f32x4 z2 = {bq[2], bq[2], bq[2], bq[2]};
        f32x4 z3 = {bq[3], bq[3], bq[3], bq[3]};
        z0 = MFMA16(ax0, Bx[0][0], z0); z0 = MFMA16(ax1, Bx[0][1], z0);
        z1 = MFMA16(ax0, Bx[1][0], z1); z1 = MFMA16(ax1, Bx[1][1], z1);
        z2 = MFMA16(ax0, Bx[2][0], z2); z2 = MFMA16(ax1, Bx[2][1], z2);
        z3 = MFMA16(ax0, Bx[3][0], z3); z3 = MFMA16(ax1, Bx[3][1], z3);
        // scatter to wave-private sXZ: row 4g+r, unit j, gates 0..3
#pragma unroll
        for (int r = 0; r < 4; ++r) {
            float4 v = {z0[r], z1[r], z2[r], z3[r]};
            *(float4*)&sXZ[w][4 * g + r][j][0] = v;
        }
        asm volatile("s_waitcnt lgkmcnt(0)" ::: "memory");  // wave-private: no barrier

        // prefetch next chunk's x (lands during the 16 steps below)
        const bool more = (n + 1 < NCHUNK);
        float4 x0, x1, x2, x3;
        if (more) {
            const float* xr = xb + ((size_t)(n + 1) * CHUNK + j) * DIM + g * 8;
            x0 = *(const float4*)(xr);
            x1 = *(const float4*)(xr + 4);
            x2 = *(const float4*)(xr + 32);
            x3 = *(const float4*)(xr + 36);
        }

        STEP(0);  STEP(1);  STEP(2);  STEP(3);
        STEP(4);  STEP(5);  STEP(6);  STEP(7);
        STEP(8);  STEP(9);  STEP(10); STEP(11);
        STEP(12); STEP(13); STEP(14); STEP(15);

        if (more) {
            ax0[0]=(f16)x0.x; ax0[1]=(f16)x0.y; ax0[2]=(f16)x0.z; ax0[3]=(f16)x0.w;
            ax0[4]=(f16)x1.x; ax0[5]=(f16)x1.y; ax0[6]=(f16)x1.z; ax0[7]=(f16)x1.w;
            ax1[0]=(f16)x2.x; ax1[1]=(f16)x2.y; ax1[2]=(f16)x2.z; ax1[3]=(f16)x2.w;
            ax1[4]=(f16)x3.x; ax1[5]=(f16)x3.y; ax1[6]=(f16)x3.z; ax1[7]=(f16)x3.w;
        }
    }
}

extern "C" void kernel_launch(void* const* d_in, const int* in_sizes, int n_in,
                              void* d_out, int out_size, void* d_ws, size_t ws_size,
                              hipStream_t stream) {
    const float* x  = (const float*)d_in[0];
    const float* Wx = (const float*)d_in[1];
    const float* Wh = (const float*)d_in[2];
    const float* b  = (const float*)d_in[3];
    float* out = (float*)d_out;

    hipLaunchKernelGGL(lstm_rrep_kernel, dim3(256), dim3(256), 0, stream,
                       x, Wx, Wh, b, out);
}